// Round 7
// baseline (304.957 us; speedup 1.0000x reference)
//
#include <hip/hip_runtime.h>
#include <math.h>

#define B_    8
#define C_    256
#define HW_   4096
#define CHW_  ((long)C_ * HW_)

#define BKT   32      // bf16 K per tile
#define LDH   40      // LDS row stride in ushorts (gemm_nt staging)
#define KS    16      // split-K for F*G^T
#define KCH   (HW_ / KS)   // 256
#define NCH   (C_ / BKT)   // 8 K-chunks in the attention GEMMs
#define NPB   32           // n-partials per row (HW_/128)

typedef __attribute__((ext_vector_type(8))) short bf16x8;
typedef __attribute__((ext_vector_type(4))) float f32x4;
#define MFMA_BF16(a, b, c) __builtin_amdgcn_mfma_f32_16x16x32_bf16((a), (b), (c), 0, 0, 0)

union frag_u { uint4 u4; bf16x8 bf; };

// async global->LDS, 16B per lane, LDS dest = wave-uniform base + lane*16
#define GLOAD_LDS16(src, dst)                                              \
    __builtin_amdgcn_global_load_lds(                                      \
        (const __attribute__((address_space(1))) void*)(src),              \
        (__attribute__((address_space(3))) void*)(dst), 16, 0, 0)

// fp32x4 -> bf16 hi + lo residual, packed 2/dword
__device__ __forceinline__ void cvt_hl4(const float4 f, uint* h, uint* l) {
    uint u0 = __float_as_uint(f.x), u1 = __float_as_uint(f.y),
         u2 = __float_as_uint(f.z), u3 = __float_as_uint(f.w);
    uint h0 = (u0 + 0x8000u) & 0xFFFF0000u, h1 = (u1 + 0x8000u) & 0xFFFF0000u,
         h2 = (u2 + 0x8000u) & 0xFFFF0000u, h3 = (u3 + 0x8000u) & 0xFFFF0000u;
    h[0] = (h0 >> 16) | h1;
    h[1] = (h2 >> 16) | h3;
    float l0 = f.x - __uint_as_float(h0), l1 = f.y - __uint_as_float(h1),
          l2 = f.z - __uint_as_float(h2), l3 = f.w - __uint_as_float(h3);
    uint a0 = __float_as_uint(l0) & 0xFFFF0000u, a1 = __float_as_uint(l1) & 0xFFFF0000u,
         a2 = __float_as_uint(l2) & 0xFFFF0000u, a3 = __float_as_uint(l3) & 0xFFFF0000u;
    l[0] = (a0 >> 16) | a1;
    l[1] = (a2 >> 16) | a3;
}
__device__ __forceinline__ void cvt_h4(const float4 f, uint* h) {
    uint u0 = __float_as_uint(f.x), u1 = __float_as_uint(f.y),
         u2 = __float_as_uint(f.z), u3 = __float_as_uint(f.w);
    uint h0 = (u0 + 0x8000u) & 0xFFFF0000u, h1 = (u1 + 0x8000u) & 0xFFFF0000u,
         h2 = (u2 + 0x8000u) & 0xFFFF0000u, h3 = (u3 + 0x8000u) & 0xFFFF0000u;
    h[0] = (h0 >> 16) | h1;
    h[1] = (h2 >> 16) | h3;
}

// 2 floats -> packed bf16 hi dword + lo-residual dword (same rounding as cvt_hl4)
__device__ __forceinline__ void cvt2_hl(float a, float b2, uint* h, uint* l) {
    uint ua = __float_as_uint(a), ub = __float_as_uint(b2);
    uint ha = (ua + 0x8000u) & 0xFFFF0000u, hb = (ub + 0x8000u) & 0xFFFF0000u;
    *h = (ha >> 16) | hb;
    float la = a - __uint_as_float(ha), lb = b2 - __uint_as_float(hb);
    *l = ((__float_as_uint(la) & 0xFFFF0000u) >> 16) | (__float_as_uint(lb) & 0xFFFF0000u);
}
__device__ __forceinline__ uint cvt2_h(float a, float b2) {
    uint ha = (__float_as_uint(a) + 0x8000u) & 0xFFFF0000u;
    uint hb = (__float_as_uint(b2) + 0x8000u) & 0xFFFF0000u;
    return (ha >> 16) | hb;
}

// Wv -> bf16 hi copy
__global__ __launch_bounds__(256) void conv_w(
    const float* __restrict__ Wv, ushort* __restrict__ Wvh)
{
    const int i = (blockIdx.x * 256 + threadIdx.x) * 4;
    float4 v = *reinterpret_cast<const float4*>(&Wv[i]);
    uint h[2];
    cvt_h4(v, h);
    *reinterpret_cast<uint2*>(&Wvh[i]) = make_uint2(h[0], h[1]);
}

// ===========================================================================
// Transpose+convert pass: maskT (bf16 hi/lo) and fgT (bf16 hi), [B,HW,C].
// ===========================================================================
__global__ __launch_bounds__(256) void transpose_cvt(
    const float* __restrict__ mask, const float* __restrict__ fg,
    ushort* __restrict__ mTh, ushort* __restrict__ mTl, ushort* __restrict__ fTh)
{
    __shared__ float Ms[64][65];
    __shared__ float Fs[64][65];

    const int b  = blockIdx.z;
    const int c0 = blockIdx.y * 64;
    const int i0 = blockIdx.x * 64;
    const int t  = threadIdx.x;

    const int lr = t >> 2;            // c-row 0..63
    const int lc = (t & 3) * 16;      // i-col base
    const float* mp = mask + (long)b * CHW_ + (long)(c0 + lr) * HW_ + i0 + lc;
    const float* fp = fg   + (long)b * CHW_ + (long)(c0 + lr) * HW_ + i0 + lc;
    #pragma unroll
    for (int j = 0; j < 16; j += 4) {
        *reinterpret_cast<float4*>(&Ms[lr][lc + j]) = *reinterpret_cast<const float4*>(mp + j);
        *reinterpret_cast<float4*>(&Fs[lr][lc + j]) = *reinterpret_cast<const float4*>(fp + j);
    }
    __syncthreads();

    const int oi = t >> 2;            // i-row 0..63
    const int oc = (t & 3) * 16;      // c base
    uint hm[8], lm[8], hf[8];
    #pragma unroll
    for (int j = 0; j < 8; ++j) {
        const float m0v = Ms[oc + 2 * j][oi], m1v = Ms[oc + 2 * j + 1][oi];
        cvt2_hl(m0v, m1v, &hm[j], &lm[j]);
        hf[j] = cvt2_h(Fs[oc + 2 * j][oi], Fs[oc + 2 * j + 1][oi]);
    }
    const long ro = ((long)b * HW_ + i0 + oi) * C_ + c0 + oc;
    *reinterpret_cast<uint4*>(&mTh[ro])     = make_uint4(hm[0], hm[1], hm[2], hm[3]);
    *reinterpret_cast<uint4*>(&mTh[ro + 8]) = make_uint4(hm[4], hm[5], hm[6], hm[7]);
    *reinterpret_cast<uint4*>(&mTl[ro])     = make_uint4(lm[0], lm[1], lm[2], lm[3]);
    *reinterpret_cast<uint4*>(&mTl[ro + 8]) = make_uint4(lm[4], lm[5], lm[6], lm[7]);
    *reinterpret_cast<uint4*>(&fTh[ro])     = make_uint4(hf[0], hf[1], hf[2], hf[3]);
    *reinterpret_cast<uint4*>(&fTh[ro + 8]) = make_uint4(hf[4], hf[5], hf[6], hf[7]);
}

// ===========================================================================
// NT MFMA GEMM (split-K, 3-pass hi/lo, in-loop cvt): part[z] = F.G^T chunk.
// Register prefetch of next chunk (issued between barriers: flies during
// ds_read+MFMA, drains at barrier#2). LDS-exchange float4 store.
// ===========================================================================
__global__ __launch_bounds__(256, 3) void gemm_nt_mfma(
    const float* __restrict__ F, const float* __restrict__ G,
    float* __restrict__ part,
    float* __restrict__ fsum, float* __restrict__ gsum)
{
    __shared__ __align__(16) ushort SMEM[4][128 * LDH];
    ushort* Ah = SMEM[0]; ushort* Al = SMEM[1];
    ushort* Bh = SMEM[2]; ushort* Bl = SMEM[3];

    const int z  = blockIdx.z;
    const int b  = z >> 4;
    const int ks = z & (KS - 1);
    const int c0 = blockIdx.y * 128;
    const int d0 = blockIdx.x * 128;
    const float* Fb = F + (long)b * CHW_ + (long)ks * KCH;
    const float* Gb = G + (long)b * CHW_ + (long)ks * KCH;
    const bool doF = (blockIdx.x == 0);
    const bool doG = (blockIdx.y == 0);

    const int t    = threadIdx.x;
    const int srow = t & 127;
    const int skf  = (t >> 7) * 16;
    const int lane = t & 63, w = t >> 6;
    const int col  = lane & 15, quad = lane >> 4;
    const int wm   = (w >> 1) * 64, wn = (w & 1) * 64;

    const float* Frow = Fb + (long)(c0 + srow) * HW_ + skf;
    const float* Grow = Gb + (long)(d0 + srow) * HW_ + skf;

    f32x4 acc[4][4] = {};
    float rsF = 0.0f, rsG = 0.0f;

    // prologue: load chunk 0 into registers
    float4 cf[4], cg[4];
    #pragma unroll
    for (int j = 0; j < 4; ++j) {
        cf[j] = *reinterpret_cast<const float4*>(Frow + j * 4);
        cg[j] = *reinterpret_cast<const float4*>(Grow + j * 4);
    }

    for (int kt = 0; kt < KCH; kt += BKT) {
        // ---- consume current regs: rowsum + cvt + LDS write ----
        if (doF) {
            #pragma unroll
            for (int j = 0; j < 4; ++j)
                rsF += (cf[j].x + cf[j].y) + (cf[j].z + cf[j].w);
        }
        if (doG) {
            #pragma unroll
            for (int j = 0; j < 4; ++j)
                rsG += (cg[j].x + cg[j].y) + (cg[j].z + cg[j].w);
        }
        {
            uint h[4], l[4];
            cvt_hl4(cf[0], h + 0, l + 0);
            cvt_hl4(cf[1], h + 2, l + 2);
            *reinterpret_cast<uint4*>(&Ah[srow * LDH + skf]) = make_uint4(h[0], h[1], h[2], h[3]);
            *reinterpret_cast<uint4*>(&Al[srow * LDH + skf]) = make_uint4(l[0], l[1], l[2], l[3]);
            cvt_hl4(cf[2], h + 0, l + 0);
            cvt_hl4(cf[3], h + 2, l + 2);
            *reinterpret_cast<uint4*>(&Ah[srow * LDH + skf + 8]) = make_uint4(h[0], h[1], h[2], h[3]);
            *reinterpret_cast<uint4*>(&Al[srow * LDH + skf + 8]) = make_uint4(l[0], l[1], l[2], l[3]);
            cvt_hl4(cg[0], h + 0, l + 0);
            cvt_hl4(cg[1], h + 2, l + 2);
            *reinterpret_cast<uint4*>(&Bh[srow * LDH + skf]) = make_uint4(h[0], h[1], h[2], h[3]);
            *reinterpret_cast<uint4*>(&Bl[srow * LDH + skf]) = make_uint4(l[0], l[1], l[2], l[3]);
            cvt_hl4(cg[2], h + 0, l + 0);
            cvt_hl4(cg[3], h + 2, l + 2);
            *reinterpret_cast<uint4*>(&Bh[srow * LDH + skf + 8]) = make_uint4(h[0], h[1], h[2], h[3]);
            *reinterpret_cast<uint4*>(&Bl[srow * LDH + skf + 8]) = make_uint4(l[0], l[1], l[2], l[3]);
        }
        __syncthreads();      // barrier#1: LDS writes visible

        // ---- issue next-chunk loads (fly during ds_read + MFMA) ----
        const bool more = (kt + BKT < KCH);
        float4 nf[4], ng[4];
        if (more) {
            #pragma unroll
            for (int j = 0; j < 4; ++j) {
                nf[j] = *reinterpret_cast<const float4*>(Frow + kt + BKT + j * 4);
                ng[j] = *reinterpret_cast<const float4*>(Grow + kt + BKT + j * 4);
            }
        }

        bf16x8 bfh[4], bfl[4];
        #pragma unroll
        for (int tj = 0; tj < 4; ++tj) {
            const int r = (wn + tj * 16 + col) * LDH + quad * 8;
            bfh[tj] = *reinterpret_cast<const bf16x8*>(&Bh[r]);
            bfl[tj] = *reinterpret_cast<const bf16x8*>(&Bl[r]);
        }
        #pragma unroll
        for (int ti = 0; ti < 4; ++ti) {
            const int r = (wm + ti * 16 + col) * LDH + quad * 8;
            bf16x8 afh = *reinterpret_cast<const bf16x8*>(&Ah[r]);
            bf16x8 afl = *reinterpret_cast<const bf16x8*>(&Al[r]);
            #pragma unroll
            for (int tj = 0; tj < 4; ++tj) {
                acc[ti][tj] = MFMA_BF16(afh, bfh[tj], acc[ti][tj]);
                acc[ti][tj] = MFMA_BF16(afh, bfl[tj], acc[ti][tj]);
                acc[ti][tj] = MFMA_BF16(afl, bfh[tj], acc[ti][tj]);
            }
        }
        __syncthreads();      // barrier#2: reads done; next-chunk loads drain here
        if (more) {
            #pragma unroll
            for (int j = 0; j < 4; ++j) { cf[j] = nf[j]; cg[j] = ng[j]; }
        }
    }

    if (doF) atomicAdd(&fsum[b * C_ + c0 + srow], rsF);
    if (doG) atomicAdd(&gsum[b * C_ + d0 + srow], rsG);

    // ---- LDS-exchange store: 32x128 fp32 patch per ti, float4 coalesced ----
    float* xch = (float*)&SMEM[0][0];          // needs 32*132*4 = 16,896 B
    float* P = part + (long)z * C_ * C_;
    const int pr = t >> 3, pu = t & 7;
    const int mmb = c0 + ((pr & 16) ? 64 : 0) + (pr & 15);
    #pragma unroll
    for (int ti = 0; ti < 4; ++ti) {
        __syncthreads();
        #pragma unroll
        for (int tj = 0; tj < 4; ++tj) {
            const int lc = wn + tj * 16 + col;
            #pragma unroll
            for (int r = 0; r < 4; ++r) {
                const int lr = (w >> 1) * 16 + quad * 4 + r;
                xch[lr * 132 + lc] = acc[ti][tj][r];
            }
        }
        __syncthreads();
        const int mm = mmb + ti * 16;
        float* dst = &P[(long)mm * C_ + d0 + pu * 16];
        const float* srcx = &xch[pr * 132 + pu * 16];
        #pragma unroll
        for (int j = 0; j < 16; j += 4)
            *reinterpret_cast<float4*>(dst + j) = *reinterpret_cast<const float4*>(srcx + j);
    }
}

// ===========================================================================
// Stats pass: 128x128 tile. B-side (maskT h/l) double-buffered via
// global_load_lds (issue-next-before-compute, one barrier per chunk);
// A-side (corr h/l) register-prefetched one chunk ahead. LDS 36 KB.
// ===========================================================================
__global__ __launch_bounds__(256, 2) void gemm_stats_mfma(
    const ushort* __restrict__ corrh, const ushort* __restrict__ corrl,
    const ushort* __restrict__ mTh,   const ushort* __restrict__ mTl,
    float* __restrict__ pmax, float* __restrict__ psum)
{
    __shared__ __align__(16) ushort S_[2][2][4096];   // [buf][Bh/Bl][128r x 32k]
    __shared__ float pm[2][128], ps[2][128];

    const int b  = blockIdx.z;
    const int m0 = blockIdx.y * 128;
    const int n0 = blockIdx.x * 128;
    const ushort* Ahb = corrh + (long)b * C_ * C_;
    const ushort* Alb = corrl + (long)b * C_ * C_;
    const ushort* Bhb = mTh + (long)b * HW_ * C_;
    const ushort* Blb = mTl + (long)b * HW_ * C_;

    const int t    = threadIdx.x;
    const int lane = t & 63, w = t >> 6;
    const int col  = lane & 15, quad = lane >> 4;
    const int wm   = (w >> 1) * 64, wn = (w & 1) * 64;
    const int qsw  = (lane & 3) ^ ((lane >> 3) & 3);   // staging k-slot swizzle
    const int srw  = lane >> 2;                        // staging row-in-16

    // B fragment byte offsets (swizzle matches staged k-slot permutation)
    int boff[4];
    long aoa[4];
    #pragma unroll
    for (int tt = 0; tt < 4; ++tt) {
        const int rowB = wn + tt * 16 + col;
        boff[tt] = rowB * 64 + ((quad ^ ((rowB >> 1) & 3)) << 4);
        aoa[tt] = (long)(m0 + wm + tt * 16 + col) * C_ + quad * 8;
    }

#define STAGE_S(buf, kk) do {                                              \
    _Pragma("unroll")                                                      \
    for (int gg = 0; gg < 2; ++gg) {                                       \
        const int rbase = w * 32 + gg * 16;                                \
        const long rsrc = rbase + srw;                                     \
        GLOAD_LDS16(Bhb + (long)(n0 + rsrc) * C_ + (kk) + qsw * 8, &S_[buf][0][rbase * 32]); \
        GLOAD_LDS16(Blb + (long)(n0 + rsrc) * C_ + (kk) + qsw * 8, &S_[buf][1][rbase * 32]); \
    }                                                                      \
} while (0)

    f32x4 acc[4][4] = {};

    // prologue
    STAGE_S(0, 0);
    bf16x8 nah[4], nal[4];
    #pragma unroll
    for (int tt = 0; tt < 4; ++tt) {
        nah[tt] = *reinterpret_cast<const bf16x8*>(&Ahb[aoa[tt]]);
        nal[tt] = *reinterpret_cast<const bf16x8*>(&Alb[aoa[tt]]);
    }
    __syncthreads();

    int cur = 0;
    #pragma unroll 1
    for (int kc = 0; kc < NCH; ++kc) {
        const int kt = kc * BKT;
        bf16x8 ah[4], al[4];
        #pragma unroll
        for (int tt = 0; tt < 4; ++tt) { ah[tt] = nah[tt]; al[tt] = nal[tt]; }

        if (kc + 1 < NCH) {
            STAGE_S(cur ^ 1, kt + BKT);
            #pragma unroll
            for (int tt = 0; tt < 4; ++tt) {
                nah[tt] = *reinterpret_cast<const bf16x8*>(&Ahb[aoa[tt] + kt + BKT]);
                nal[tt] = *reinterpret_cast<const bf16x8*>(&Alb[aoa[tt] + kt + BKT]);
            }
        }

        const char* base = (const char*)&S_[cur][0][0];
        bf16x8 bh[4], bl[4];
        #pragma unroll
        for (int tt = 0; tt < 4; ++tt) {
            bh[tt] = *reinterpret_cast<const bf16x8*>(base + boff[tt]);
            bl[tt] = *reinterpret_cast<const bf16x8*>(base + 8192 + boff[tt]);
        }
        #pragma unroll
        for (int tj = 0; tj < 4; ++tj) {
            #pragma unroll
            for (int ti = 0; ti < 4; ++ti) {
                acc[ti][tj] = MFMA_BF16(ah[ti], bh[tj], acc[ti][tj]);
                acc[ti][tj] = MFMA_BF16(ah[ti], bl[tj], acc[ti][tj]);
                acc[ti][tj] = MFMA_BF16(al[ti], bh[tj], acc[ti][tj]);
            }
        }
        __syncthreads();      // next-buf stage loads drain here (post-compute)
        cur ^= 1;
    }
#undef STAGE_S

    // per-tile softmax partials (max & sum-exp over this block's 128 i's)
    #pragma unroll
    for (int ti = 0; ti < 4; ++ti) {
        #pragma unroll
        for (int r = 0; r < 4; ++r) {
            float mx = fmaxf(fmaxf(acc[ti][0][r], acc[ti][1][r]),
                             fmaxf(acc[ti][2][r], acc[ti][3][r]));
            mx = fmaxf(mx, __shfl_xor(mx, 1));
            mx = fmaxf(mx, __shfl_xor(mx, 2));
            mx = fmaxf(mx, __shfl_xor(mx, 4));
            mx = fmaxf(mx, __shfl_xor(mx, 8));
            float se2 = __expf(acc[ti][0][r] - mx) + __expf(acc[ti][1][r] - mx)
                      + __expf(acc[ti][2][r] - mx) + __expf(acc[ti][3][r] - mx);
            se2 += __shfl_xor(se2, 1);
            se2 += __shfl_xor(se2, 2);
            se2 += __shfl_xor(se2, 4);
            se2 += __shfl_xor(se2, 8);
            if (col == 0) {
                const int rb = wm + ti * 16 + quad * 4 + r;
                pm[w & 1][rb] = mx;
                ps[w & 1][rb] = se2;
            }
        }
    }
    __syncthreads();
    if (t < 128) {
        const float a0 = pm[0][t], a1 = pm[1][t];
        const float gm = fmaxf(a0, a1);
        const float gs = ps[0][t] * __expf(a0 - gm) + ps[1][t] * __expf(a1 - gm);
        const long rowg = (long)b * C_ + m0 + t;
        pmax[rowg * NPB + blockIdx.x] = gm;
        psum[rowg * NPB + blockIdx.x] = gs;
    }
}

// ===========================================================================
// Fused final: 128x128 tile. B-side (maskT h/l, fgT) double-buffered via
// global_load_lds; corr h/l register-prefetched; Wvh at-use (L2-hot 128KB —
// prefetching it would exceed the 256-reg unified budget). One barrier/chunk.
// ===========================================================================
__global__ __launch_bounds__(256, 2) void gemm_fused_final(
    const ushort* __restrict__ corrh, const ushort* __restrict__ corrl,
    const ushort* __restrict__ Wvh,
    const ushort* __restrict__ mTh,   const ushort* __restrict__ mTl,
    const ushort* __restrict__ fTh,
    const float* __restrict__ mask,   const float* __restrict__ fg,
    const float* __restrict__ pmax,   const float* __restrict__ psum,
    const float* __restrict__ bv,     const float* __restrict__ gamma,
    float* __restrict__ out)
{
    __shared__ __align__(16) ushort S_[2][3][4096];   // [buf][Bh/Bl/Bf][128x32]
    __shared__ float sm[128], si[128];

    const int b  = blockIdx.z;
    const int m0 = blockIdx.y * 128;        // c
    const int n0 = blockIdx.x * 128;        // i
    const ushort* Ahb = corrh + (long)b * C_ * C_;
    const ushort* Alb = corrl + (long)b * C_ * C_;
    const ushort* Bhb = mTh + (long)b * HW_ * C_;
    const ushort* Blb = mTl + (long)b * HW_ * C_;
    const ushort* Bfb = fTh + (long)b * HW_ * C_;

    const int t    = threadIdx.x;
    const int lane = t & 63, w = t >> 6;
    const int col  = lane & 15, quad = lane >> 4;
    const int wm   = (w >> 1) * 64, wn = (w & 1) * 64;
    const int qsw  = (lane & 3) ^ ((lane >> 3) & 3);
    const int srw  = lane >> 2;

    // ---- coalesced softmax-stat combine: 2 lanes per row, 4x float4 each ----
    {
        const int row  = t >> 1;
        const int part = t & 1;
        const long rowg = (long)b * C_ + m0 + row;
        const float* pmr = pmax + rowg * NPB + part * 16;
        const float* psr = psum + rowg * NPB + part * 16;
        float4 pv[4], sv[4];
        #pragma unroll
        for (int j = 0; j < 4; ++j) {
            pv[j] = *reinterpret_cast<const float4*>(pmr + j * 4);
            sv[j] = *reinterpret_cast<const float4*>(psr + j * 4);
        }
        float gm = -INFINITY;
        #pragma unroll
        for (int j = 0; j < 4; ++j)
            gm = fmaxf(gm, fmaxf(fmaxf(pv[j].x, pv[j].y), fmaxf(pv[j].z, pv[j].w)));
        gm = fmaxf(gm, __shfl_xor(gm, 1));
        float gs = 0.0f;
        #pragma unroll
        for (int j = 0; j < 4; ++j) {
            gs += sv[j].x * __expf(pv[j].x - gm) + sv[j].y * __expf(pv[j].y - gm)
                + sv[j].z * __expf(pv[j].z - gm) + sv[j].w * __expf(pv[j].w - gm);
        }
        gs += __shfl_xor(gs, 1);
        sm[row] = gm;
        si[row] = 1.0f / gs;
    }

    int boff[4];
    long aoa[4];
    #pragma unroll
    for (int tt = 0; tt < 4; ++tt) {
        const int rowB = wn + tt * 16 + col;
        boff[tt] = rowB * 64 + ((quad ^ ((rowB >> 1) & 3)) << 4);
        aoa[tt] = (long)(m0 + wm + tt * 16 + col) * C_ + quad * 8;
    }

#define STAGE_F(buf, kk) do {                                              \
    _Pragma("unroll")                                                      \
    for (int gg = 0; gg < 2; ++gg) {                                       \
        const int rbase = w * 32 + gg * 16;                                \
        const long rsrc = rbase + srw;                                     \
        GLOAD_LDS16(Bhb + (long)(n0 + rsrc) * C_ + (kk) + qsw * 8, &S_[buf][0][rbase * 32]); \
        GLOAD_LDS16(Blb + (long)(n0 + rsrc) * C_ + (kk) + qsw * 8, &S_[buf][1][rbase * 32]); \
        GLOAD_LDS16(Bfb + (long)(n0 + rsrc) * C_ + (kk) + qsw * 8, &S_[buf][2][rbase * 32]); \
    }                                                                      \
} while (0)

    f32x4 acc_s[4][4] = {};
    f32x4 acc_v[4][4] = {};

    // prologue
    STAGE_F(0, 0);
    bf16x8 nah[4], nal[4];
    #pragma unroll
    for (int tt = 0; tt < 4; ++tt) {
        nah[tt] = *reinterpret_cast<const bf16x8*>(&Ahb[aoa[tt]]);
        nal[tt] = *reinterpret_cast<const bf16x8*>(&Alb[aoa[tt]]);
    }
    __syncthreads();

    int cur = 0;
    #pragma unroll 1
    for (int kc = 0; kc < NCH; ++kc) {
        const int kt = kc * BKT;
        bf16x8 ah[4], al[4], aw[4];
        #pragma unroll
        for (int tt = 0; tt < 4; ++tt) { ah[tt] = nah[tt]; al[tt] = nal[tt]; }
        #pragma unroll
        for (int tt = 0; tt < 4; ++tt)
            aw[tt] = *reinterpret_cast<const bf16x8*>(&Wvh[aoa[tt] + kt]);

        if (kc + 1 < NCH) {
            STAGE_F(cur ^ 1, kt + BKT);
            #pragma unroll
            for (int tt = 0; tt < 4; ++tt) {
                nah[tt] = *reinterpret_cast<const bf16x8*>(&Ahb[aoa[tt] + kt + BKT]);
                nal[tt] = *reinterpret_cast<const bf16x8*>(&Alb[aoa[tt] + kt + BKT]);
            }
        }

        const char* base = (const char*)&S_[cur][0][0];
        bf16x8 bh[4], bl[4], bf[4];
        #pragma unroll
        for (int tt = 0; tt < 4; ++tt) {
            bh[tt] = *reinterpret_cast<const bf16x8*>(base + boff[tt]);
            bl[tt] = *reinterpret_cast<const bf16x8*>(base + 8192 + boff[tt]);
            bf[tt] = *reinterpret_cast<const bf16x8*>(base + 16384 + boff[tt]);
        }
        #pragma unroll
        for (int tj = 0; tj < 4; ++tj) {
            #pragma unroll
            for (int ti = 0; ti < 4; ++ti) {
                acc_s[ti][tj] = MFMA_BF16(ah[ti], bh[tj], acc_s[ti][tj]);
                acc_s[ti][tj] = MFMA_BF16(ah[ti], bl[tj], acc_s[ti][tj]);
                acc_s[ti][tj] = MFMA_BF16(al[ti], bh[tj], acc_s[ti][tj]);
                acc_v[ti][tj] = MFMA_BF16(aw[ti], bf[tj], acc_v[ti][tj]);
            }
        }
        __syncthreads();      // next-buf stage loads drain here (post-compute)
        cur ^= 1;
    }
#undef STAGE_F

    // scores -> gamma-scaled probabilities
    const float g = gamma[0];
    #pragma unroll
    for (int ti = 0; ti < 4; ++ti) {
        #pragma unroll
        for (int r = 0; r < 4; ++r) {
            const int lrow = wm + ti * 16 + quad * 4 + r;
            const float mx  = sm[lrow];
            const float inv = si[lrow] * g;
            #pragma unroll
            for (int tj = 0; tj < 4; ++tj)
                acc_s[ti][tj][r] = __expf(acc_s[ti][tj][r] - mx) * inv;
        }
    }

    // epilogue
    #pragma unroll
    for (int ti = 0; ti < 4; ++ti) {
        const int m = m0 + wm + ti * 16 + quad * 4;
        #pragma unroll
        for (int r = 0; r < 4; ++r) {
            const float bvm = bv[m + r];
            #pragma unroll
            for (int tj = 0; tj < 4; ++tj) {
                const int n = n0 + wn + tj * 16 + col;
                const long e = (long)b * CHW_ + (long)(m + r) * HW_ + n;
                const float f  = fg[e];
                const float mk = mask[e];
                const float vv = acc_v[ti][tj][r] + bvm;
                out[e] = f * mk + (1.0f - mk) * acc_s[ti][tj][r] * vv;
            }
        }
    }
}

// ===========================================================================
// reduce split-K partials (float4)
// ===========================================================================
__global__ __launch_bounds__(256) void reduce_part(
    const float* __restrict__ part, float* __restrict__ S1)
{
    const long i4 = ((long)blockIdx.x * 256 + threadIdx.x) * 4;
    const int  b  = (int)(i4 >> 16);
    const long e  = i4 & 65535;
    const float* p = part + ((long)b * KS) * 65536 + e;
    float4 s = make_float4(0.f, 0.f, 0.f, 0.f);
    #pragma unroll
    for (int ks = 0; ks < KS; ++ks) {
        float4 v = *reinterpret_cast<const float4*>(&p[(long)ks * 65536]);
        s.x += v.x; s.y += v.y; s.z += v.z; s.w += v.w;
    }
    *reinterpret_cast<float4*>(&S1[i4]) = s;
}

#define BK64 16
#define LDT64 68
__global__ __launch_bounds__(256) void gemm_nt64(
    const float* __restrict__ S1, const float* __restrict__ Wk,
    float* __restrict__ T)
{
    __shared__ float As[BK64][LDT64];
    __shared__ float Bs[BK64][LDT64];
    const int r0 = blockIdx.y * 64;
    const int d0 = blockIdx.x * 64;
    const int t   = threadIdx.x;
    const int tx  = t & 15, ty = t >> 4;
    const int tx4 = tx * 4, ty4 = ty * 4;
    const int am  = t >> 2, ak4 = (t & 3) * 4;

    float acc[4][4] = {};
    for (int k0 = 0; k0 < C_; k0 += BK64) {
        float4 av = *reinterpret_cast<const float4*>(&S1[(long)(r0 + am) * C_ + k0 + ak4]);
        float4 bw = *reinterpret_cast<const float4*>(&Wk[(long)(d0 + am) * C_ + k0 + ak4]);
        As[ak4+0][am]=av.x; As[ak4+1][am]=av.y; As[ak4+2][am]=av.z; As[ak4+3][am]=av.w;
        Bs[ak4+0][am]=bw.x; Bs[ak4+1][am]=bw.y; Bs[ak4+2][am]=bw.z; Bs[ak4+3][am]=bw.w;
        __syncthreads();
        #pragma unroll
        for (int kk = 0; kk < BK64; ++kk) {
            float4 a = *reinterpret_cast<const float4*>(&As[kk][ty4]);
            float4 x = *reinterpret_cast<const float4*>(&Bs[kk][tx4]);
            const float ar[4] = {a.x,a.y,a.z,a.w};
            const float xr[4] = {x.x,x.y,x.z,x.w};
            #pragma unroll
            for (int r = 0; r < 4; ++r)
                #pragma unroll
                for (int s = 0; s < 4; ++s)
                    acc[r][s] = fmaf(ar[r], xr[s], acc[r][s]);
        }
        __syncthreads();
    }
    #pragma unroll
    for (int r = 0; r < 4; ++r) {
        float4 o; o.x=acc[r][0]; o.y=acc[r][1]; o.z=acc[r][2]; o.w=acc[r][3];
        *reinterpret_cast<float4*>(&T[(long)(r0 + ty4 + r) * C_ + d0 + tx4]) = o;
    }
}

// corr = Wq*T + u*bk^T + bq*wh^T -> bf16 h/l.  u, wh computed inline.
__global__ __launch_bounds__(256) void gemm_nn64_rank1(
    const float* __restrict__ Wq, const float* __restrict__ T,
    const float* __restrict__ Wk, const float* __restrict__ bk,
    const float* __restrict__ bq,
    const float* __restrict__ fsum, const float* __restrict__ gsum,
    ushort* __restrict__ corrh, ushort* __restrict__ corrl)
{
    __shared__ float As[BK64][LDT64];
    __shared__ float Bs[BK64][LDT64];
    __shared__ float u_s[64], wh_s[64];
    const int b  = blockIdx.z;
    const int m0 = blockIdx.y * 64;
    const int n0 = blockIdx.x * 64;
    const float* Tb = T + (long)b * C_ * C_;

    const int t   = threadIdx.x;
    const int tx  = t & 15, ty = t >> 4;
    const int tx4 = tx * 4, ty4 = ty * 4;
    const int am  = t >> 2, ak4 = (t & 3) * 4;
    const int xk  = ty,     xn4 = tx4;

    if (t < 64) {
        const float* wrow = Wq + (long)(m0 + t) * C_;
        const float* s = fsum + b * C_;
        float a = 0.0f;
        for (int e2 = 0; e2 < C_; ++e2) a = fmaf(wrow[e2], s[e2], a);
        u_s[t] = a;
    } else if (t < 128) {
        const int d = n0 + (t - 64);
        const float* wrow = Wk + (long)d * C_;
        const float* s = gsum + b * C_;
        float a = 0.0f;
        for (int e2 = 0; e2 < C_; ++e2) a = fmaf(wrow[e2], s[e2], a);
        wh_s[t - 64] = a + (float)HW_ * bk[d];
    }

    float acc[4][4] = {};
    for (int k0 = 0; k0 < C_; k0 += BK64) {
        float4 av = *reinterpret_cast<const float4*>(&Wq[(long)(m0 + am) * C_ + k0 + ak4]);
        float4 xv = *reinterpret_cast<const float4*>(&Tb[(long)(k0 + xk) * C_ + n0 + xn4]);
        As[ak4+0][am]=av.x; As[ak4+1][am]=av.y; As[ak4+2][am]=av.z; As[ak4+3][am]=av.w;
        *reinterpret_cast<float4*>(&Bs[xk][xn4]) = xv;
        __syncthreads();
        #pragma unroll
        for (int kk = 0; kk < BK64; ++kk) {
            float4 a = *reinterpret_cast<const float4*>(&As[kk][ty4]);
            float4 x = *reinterpret_cast<const float4*>(&Bs[kk][tx4]);
            const float ar[4] = {a.x,a.y,a.z,a.w};
            const float xr[4] = {x.x,x.y,x.z,x.w};
            #pragma unroll
            for (int r = 0; r < 4; ++r)
                #pragma unroll
                for (int s = 0; s < 4; ++s)
                    acc[r][s] = fmaf(ar[r], xr[s], acc[r][s]);
        }
        __syncthreads();
    }

    float4 bkv = *reinterpret_cast<const float4*>(&bk[n0 + tx4]);
    float4 whv = make_float4(wh_s[tx4], wh_s[tx4+1], wh_s[tx4+2], wh_s[tx4+3]);
    #pragma unroll
    for (int r = 0; r < 4; ++r) {
        const int m = m0 + ty4 + r;
        const float um = u_s[ty4 + r];
        const float bm = bq[m];
        float4 o;
        o.x = acc[r][0] + um*bkv.x + bm*whv.x;
        o.y = acc[r][1] + um*bkv.y + bm*whv.y;
        o.z = acc[r][2] + um*bkv.z + bm*whv.z;
        o.w = acc[r][3] + um*bkv.w + bm*whv.w;
        uint h[2], l[2];
        cvt_hl4(o, h, l);
        const long e = (long)b * C_ * C_ + (long)m * C_ + n0 + tx4;
        *reinterpret_cast<uint2*>(&corrh[e]) = make_uint2(h[0], h[1]);
        *reinterpret_cast<uint2*>(&corrl[e]) = make_uint2(l[0], l[1]);
    }
}

// ===========================================================================
extern "C" void kernel_launch(void* const* d_in, const int* in_sizes, int n_in,
                              void* d_out, int out_size, void* d_ws, size_t ws_size,
                              hipStream_t stream)
{
    const float* fg    = (const float*)d_in[0];
    const float* bg    = (const float*)d_in[1];
    const float* mask  = (const float*)d_in[2];
    const float* Wq    = (const float*)d_in[3];
    const float* bq    = (const float*)d_in[4];
    const float* Wk    = (const float*)d_in[5];
    const float* bk    = (const float*)d_in[6];
    const float* Wv    = (const float*)d_in[7];
    const float* bv    = (const float*)d_in[8];
    const float* gamma = (const float*)d_in[9];
    float* out = (float*)d_out;

    // ---- workspace layout (bytes), total 57,294,848 ----
    // part (33.5 MB) dead after reduce_part -> aliased by mTh/mTl.
    // S1 (2 MB) dead after gemm_nt64 -> aliased by pmax/psum.
    char* ws = (char*)d_ws;
    float*  part   = (float*)(ws);                        // 33,554,432
    float*  S1     = (float*)(ws + 33554432);             // 2,097,152
    float*  T      = (float*)(ws + 35651584);             // 2,097,152
    ushort* corrh  = (ushort*)(ws + 37748736);            // 1,048,576
    ushort* corrl  = (ushort*)(ws + 38797312);            // 1,048,576
    ushort* Wvh    = (ushort*)(ws + 39845888);            // 131,072
    float*  fsum   = (float*)(ws + 39976960);             // 8,192
    float*  gsum   = (float*)(ws + 39985152);             // 8,192
    float*  pmax   = (float*)(ws + 33554432);             // 262,144 (alias S1)
    float*  psum   = (float*)(ws + 33816576);             // 262,144 (alias S1)
    ushort* mTh    = (ushort*)(ws);                       // 16,777,216 (alias part)
    ushort* mTl    = (ushort*)(ws + 16777216);            // 16,777,216 (alias part)
    ushort* fTh    = (ushort*)(ws + 40517632);            // 16,777,216

    const dim3 blk(256);

    // 0. zero the atomic accumulators (fsum+gsum contiguous 16 kB)
    hipMemsetAsync(fsum, 0, 16384, stream);

    // 1. Wv -> bf16 hi
    conv_w<<<dim3(64), blk, 0, stream>>>(Wv, Wvh);

    // 2. S1 = F*G^T via split-K MFMA (fused row sums), reduce
    gemm_nt_mfma<<<dim3(2, 2, B_ * KS), blk, 0, stream>>>(fg, bg, part, fsum, gsum);
    reduce_part<<<dim3(B_ * C_ * C_ / 1024), blk, 0, stream>>>(part, S1);

    // 2b. transposed bf16 operands (after reduce_part: part region is reused)
    transpose_cvt<<<dim3(HW_ / 64, C_ / 64, B_), blk, 0, stream>>>(
        mask, fg, mTh, mTl, fTh);

    // 3. T = S1 * Wk^T ; corr (bf16 h/l) = Wq*T + u*bk^T + bq*wh^T (uvw inline)
    gemm_nt64<<<dim3(C_ / 64, B_ * C_ / 64), blk, 0, stream>>>(S1, Wk, T);
    gemm_nn64_rank1<<<dim3(4, 4, B_), blk, 0, stream>>>(
        Wq, T, Wk, bk, bq, fsum, gsum, corrh, corrl);

    // 4. stats pass (dbuf B-staging, reg-prefetched A, 1 barrier/chunk)
    gemm_stats_mfma<<<dim3(HW_ / 128, C_ / 128, B_), blk, 0, stream>>>(
        corrh, corrl, mTh, mTl, pmax, psum);

    // 5. fused recompute + v-GEMM + finalize (dbuf B-staging, reg-prefetched A)
    gemm_fused_final<<<dim3(HW_ / 128, C_ / 128, B_), blk, 0, stream>>>(
        corrh, corrl, Wvh, mTh, mTl, fTh, mask, fg, pmax, psum, bv, gamma, out);
}

// Round 8
// 279.155 us; speedup vs baseline: 1.0924x; 1.0924x over previous
//
#include <hip/hip_runtime.h>
#include <math.h>

#define B_    8
#define C_    256
#define HW_   4096
#define CHW_  ((long)C_ * HW_)

#define BKT   32      // bf16 K per tile
#define LDH   40      // LDS row stride in ushorts (gemm_nt staging)
#define KS    16      // split-K for F*G^T
#define KCH   (HW_ / KS)   // 256
#define NCH   (C_ / BKT)   // 8 K-chunks in the attention GEMMs
#define NPB   32           // n-partials per row (HW_/128)

typedef __attribute__((ext_vector_type(8))) short bf16x8;
typedef __attribute__((ext_vector_type(4))) float f32x4;
#define MFMA_BF16(a, b, c) __builtin_amdgcn_mfma_f32_16x16x32_bf16((a), (b), (c), 0, 0, 0)

union frag_u { uint4 u4; bf16x8 bf; };

// async global->LDS, 16B per lane, LDS dest = wave-uniform base + lane*16
#define GLOAD_LDS16(src, dst)                                              \
    __builtin_amdgcn_global_load_lds(                                      \
        (const __attribute__((address_space(1))) void*)(src),              \
        (__attribute__((address_space(3))) void*)(dst), 16, 0, 0)

// fp32x4 -> bf16 hi + lo residual, packed 2/dword
__device__ __forceinline__ void cvt_hl4(const float4 f, uint* h, uint* l) {
    uint u0 = __float_as_uint(f.x), u1 = __float_as_uint(f.y),
         u2 = __float_as_uint(f.z), u3 = __float_as_uint(f.w);
    uint h0 = (u0 + 0x8000u) & 0xFFFF0000u, h1 = (u1 + 0x8000u) & 0xFFFF0000u,
         h2 = (u2 + 0x8000u) & 0xFFFF0000u, h3 = (u3 + 0x8000u) & 0xFFFF0000u;
    h[0] = (h0 >> 16) | h1;
    h[1] = (h2 >> 16) | h3;
    float l0 = f.x - __uint_as_float(h0), l1 = f.y - __uint_as_float(h1),
          l2 = f.z - __uint_as_float(h2), l3 = f.w - __uint_as_float(h3);
    uint a0 = __float_as_uint(l0) & 0xFFFF0000u, a1 = __float_as_uint(l1) & 0xFFFF0000u,
         a2 = __float_as_uint(l2) & 0xFFFF0000u, a3 = __float_as_uint(l3) & 0xFFFF0000u;
    l[0] = (a0 >> 16) | a1;
    l[1] = (a2 >> 16) | a3;
}
__device__ __forceinline__ void cvt_h4(const float4 f, uint* h) {
    uint u0 = __float_as_uint(f.x), u1 = __float_as_uint(f.y),
         u2 = __float_as_uint(f.z), u3 = __float_as_uint(f.w);
    uint h0 = (u0 + 0x8000u) & 0xFFFF0000u, h1 = (u1 + 0x8000u) & 0xFFFF0000u,
         h2 = (u2 + 0x8000u) & 0xFFFF0000u, h3 = (u3 + 0x8000u) & 0xFFFF0000u;
    h[0] = (h0 >> 16) | h1;
    h[1] = (h2 >> 16) | h3;
}

// 2 floats -> packed bf16 hi dword + lo-residual dword (same rounding as cvt_hl4)
__device__ __forceinline__ void cvt2_hl(float a, float b2, uint* h, uint* l) {
    uint ua = __float_as_uint(a), ub = __float_as_uint(b2);
    uint ha = (ua + 0x8000u) & 0xFFFF0000u, hb = (ub + 0x8000u) & 0xFFFF0000u;
    *h = (ha >> 16) | hb;
    float la = a - __uint_as_float(ha), lb = b2 - __uint_as_float(hb);
    *l = ((__float_as_uint(la) & 0xFFFF0000u) >> 16) | (__float_as_uint(lb) & 0xFFFF0000u);
}
__device__ __forceinline__ uint cvt2_h(float a, float b2) {
    uint ha = (__float_as_uint(a) + 0x8000u) & 0xFFFF0000u;
    uint hb = (__float_as_uint(b2) + 0x8000u) & 0xFFFF0000u;
    return (ha >> 16) | hb;
}

// ===========================================================================
// NT MFMA GEMM (split-K, 3-pass hi/lo, in-loop cvt): part[z] = F.G^T chunk.
// Register prefetch of next chunk (issued between barriers: flies during
// ds_read+MFMA, drains at barrier#2). LDS-exchange float4 store.
// ===========================================================================
__global__ __launch_bounds__(256, 3) void gemm_nt_mfma(
    const float* __restrict__ F, const float* __restrict__ G,
    float* __restrict__ part,
    float* __restrict__ fsum, float* __restrict__ gsum)
{
    __shared__ __align__(16) ushort SMEM[4][128 * LDH];
    ushort* Ah = SMEM[0]; ushort* Al = SMEM[1];
    ushort* Bh = SMEM[2]; ushort* Bl = SMEM[3];

    const int z  = blockIdx.z;
    const int b  = z >> 4;
    const int ks = z & (KS - 1);
    const int c0 = blockIdx.y * 128;
    const int d0 = blockIdx.x * 128;
    const float* Fb = F + (long)b * CHW_ + (long)ks * KCH;
    const float* Gb = G + (long)b * CHW_ + (long)ks * KCH;
    const bool doF = (blockIdx.x == 0);
    const bool doG = (blockIdx.y == 0);

    const int t    = threadIdx.x;
    const int srow = t & 127;
    const int skf  = (t >> 7) * 16;
    const int lane = t & 63, w = t >> 6;
    const int col  = lane & 15, quad = lane >> 4;
    const int wm   = (w >> 1) * 64, wn = (w & 1) * 64;

    const float* Frow = Fb + (long)(c0 + srow) * HW_ + skf;
    const float* Grow = Gb + (long)(d0 + srow) * HW_ + skf;

    f32x4 acc[4][4] = {};
    float rsF = 0.0f, rsG = 0.0f;

    // prologue: load chunk 0 into registers
    float4 cf[4], cg[4];
    #pragma unroll
    for (int j = 0; j < 4; ++j) {
        cf[j] = *reinterpret_cast<const float4*>(Frow + j * 4);
        cg[j] = *reinterpret_cast<const float4*>(Grow + j * 4);
    }

    for (int kt = 0; kt < KCH; kt += BKT) {
        // ---- consume current regs: rowsum + cvt + LDS write ----
        if (doF) {
            #pragma unroll
            for (int j = 0; j < 4; ++j)
                rsF += (cf[j].x + cf[j].y) + (cf[j].z + cf[j].w);
        }
        if (doG) {
            #pragma unroll
            for (int j = 0; j < 4; ++j)
                rsG += (cg[j].x + cg[j].y) + (cg[j].z + cg[j].w);
        }
        {
            uint h[4], l[4];
            cvt_hl4(cf[0], h + 0, l + 0);
            cvt_hl4(cf[1], h + 2, l + 2);
            *reinterpret_cast<uint4*>(&Ah[srow * LDH + skf]) = make_uint4(h[0], h[1], h[2], h[3]);
            *reinterpret_cast<uint4*>(&Al[srow * LDH + skf]) = make_uint4(l[0], l[1], l[2], l[3]);
            cvt_hl4(cf[2], h + 0, l + 0);
            cvt_hl4(cf[3], h + 2, l + 2);
            *reinterpret_cast<uint4*>(&Ah[srow * LDH + skf + 8]) = make_uint4(h[0], h[1], h[2], h[3]);
            *reinterpret_cast<uint4*>(&Al[srow * LDH + skf + 8]) = make_uint4(l[0], l[1], l[2], l[3]);
            cvt_hl4(cg[0], h + 0, l + 0);
            cvt_hl4(cg[1], h + 2, l + 2);
            *reinterpret_cast<uint4*>(&Bh[srow * LDH + skf]) = make_uint4(h[0], h[1], h[2], h[3]);
            *reinterpret_cast<uint4*>(&Bl[srow * LDH + skf]) = make_uint4(l[0], l[1], l[2], l[3]);
            cvt_hl4(cg[2], h + 0, l + 0);
            cvt_hl4(cg[3], h + 2, l + 2);
            *reinterpret_cast<uint4*>(&Bh[srow * LDH + skf + 8]) = make_uint4(h[0], h[1], h[2], h[3]);
            *reinterpret_cast<uint4*>(&Bl[srow * LDH + skf + 8]) = make_uint4(l[0], l[1], l[2], l[3]);
        }
        __syncthreads();      // barrier#1: LDS writes visible

        // ---- issue next-chunk loads (fly during ds_read + MFMA) ----
        const bool more = (kt + BKT < KCH);
        float4 nf[4], ng[4];
        if (more) {
            #pragma unroll
            for (int j = 0; j < 4; ++j) {
                nf[j] = *reinterpret_cast<const float4*>(Frow + kt + BKT + j * 4);
                ng[j] = *reinterpret_cast<const float4*>(Grow + kt + BKT + j * 4);
            }
        }

        bf16x8 bfh[4], bfl[4];
        #pragma unroll
        for (int tj = 0; tj < 4; ++tj) {
            const int r = (wn + tj * 16 + col) * LDH + quad * 8;
            bfh[tj] = *reinterpret_cast<const bf16x8*>(&Bh[r]);
            bfl[tj] = *reinterpret_cast<const bf16x8*>(&Bl[r]);
        }
        #pragma unroll
        for (int ti = 0; ti < 4; ++ti) {
            const int r = (wm + ti * 16 + col) * LDH + quad * 8;
            bf16x8 afh = *reinterpret_cast<const bf16x8*>(&Ah[r]);
            bf16x8 afl = *reinterpret_cast<const bf16x8*>(&Al[r]);
            #pragma unroll
            for (int tj = 0; tj < 4; ++tj) {
                acc[ti][tj] = MFMA_BF16(afh, bfh[tj], acc[ti][tj]);
                acc[ti][tj] = MFMA_BF16(afh, bfl[tj], acc[ti][tj]);
                acc[ti][tj] = MFMA_BF16(afl, bfh[tj], acc[ti][tj]);
            }
        }
        __syncthreads();      // barrier#2: reads done; next-chunk loads drain here
        if (more) {
            #pragma unroll
            for (int j = 0; j < 4; ++j) { cf[j] = nf[j]; cg[j] = ng[j]; }
        }
    }

    if (doF) atomicAdd(&fsum[b * C_ + c0 + srow], rsF);
    if (doG) atomicAdd(&gsum[b * C_ + d0 + srow], rsG);

    // ---- LDS-exchange store: 32x128 fp32 patch per ti, float4 coalesced ----
    float* xch = (float*)&SMEM[0][0];          // needs 32*132*4 = 16,896 B
    float* P = part + (long)z * C_ * C_;
    const int pr = t >> 3, pu = t & 7;
    const int mmb = c0 + ((pr & 16) ? 64 : 0) + (pr & 15);
    #pragma unroll
    for (int ti = 0; ti < 4; ++ti) {
        __syncthreads();
        #pragma unroll
        for (int tj = 0; tj < 4; ++tj) {
            const int lc = wn + tj * 16 + col;
            #pragma unroll
            for (int r = 0; r < 4; ++r) {
                const int lr = (w >> 1) * 16 + quad * 4 + r;
                xch[lr * 132 + lc] = acc[ti][tj][r];
            }
        }
        __syncthreads();
        const int mm = mmb + ti * 16;
        float* dst = &P[(long)mm * C_ + d0 + pu * 16];
        const float* srcx = &xch[pr * 132 + pu * 16];
        #pragma unroll
        for (int j = 0; j < 16; j += 4)
            *reinterpret_cast<float4*>(dst + j) = *reinterpret_cast<const float4*>(srcx + j);
    }
}

// ===========================================================================
// reduce split-K partials (float4)
// ===========================================================================
__global__ __launch_bounds__(256) void reduce_part(
    const float* __restrict__ part, float* __restrict__ S1)
{
    const long i4 = ((long)blockIdx.x * 256 + threadIdx.x) * 4;
    const int  b  = (int)(i4 >> 16);
    const long e  = i4 & 65535;
    const float* p = part + ((long)b * KS) * 65536 + e;
    float4 s = make_float4(0.f, 0.f, 0.f, 0.f);
    #pragma unroll
    for (int ks = 0; ks < KS; ++ks) {
        float4 v = *reinterpret_cast<const float4*>(&p[(long)ks * 65536]);
        s.x += v.x; s.y += v.y; s.z += v.z; s.w += v.w;
    }
    *reinterpret_cast<float4*>(&S1[i4]) = s;
}

// ===========================================================================
// mid_pass: merged transpose_cvt (z<8) + gemm_nt64 (z==8, flat<128) +
// conv_w (z==8, flat in [128,192)). One launch instead of three — the
// ~11 us/launch fixed overhead is comparable to a kernel optimization.
// All three branches run after reduce_part; mutually independent.
// ===========================================================================
#define BK64 16
#define LDT64 68
__global__ __launch_bounds__(256) void mid_pass(
    const float* __restrict__ mask, const float* __restrict__ fg,
    ushort* __restrict__ mTh, ushort* __restrict__ mTl, ushort* __restrict__ fTh,
    const float* __restrict__ S1, const float* __restrict__ Wk,
    float* __restrict__ T,
    const float* __restrict__ Wv, ushort* __restrict__ Wvh)
{
    __shared__ float SH[8320];   // 33,280 B: transpose uses all; nt64 uses 8.7KB

    const int t = threadIdx.x;
    const int z = blockIdx.z;

    if (z < 8) {
        // ---------------- transpose_cvt branch ----------------
        const int b  = z;
        const int c0 = blockIdx.y * 64;
        const int i0 = blockIdx.x * 64;
        float* Ms = SH;              // [64][65]
        float* Fs = SH + 4160;       // [64][65]

        const int lr = t >> 2;            // c-row 0..63
        const int lc = (t & 3) * 16;      // i-col base
        const float* mp = mask + (long)b * CHW_ + (long)(c0 + lr) * HW_ + i0 + lc;
        const float* fp = fg   + (long)b * CHW_ + (long)(c0 + lr) * HW_ + i0 + lc;
        #pragma unroll
        for (int j = 0; j < 16; j += 4) {
            *reinterpret_cast<float4*>(&Ms[lr * 65 + lc + j]) = *reinterpret_cast<const float4*>(mp + j);
            *reinterpret_cast<float4*>(&Fs[lr * 65 + lc + j]) = *reinterpret_cast<const float4*>(fp + j);
        }
        __syncthreads();

        const int oi = t >> 2;            // i-row 0..63
        const int oc = (t & 3) * 16;      // c base
        uint hm[8], lm[8], hf[8];
        #pragma unroll
        for (int j = 0; j < 8; ++j) {
            const float m0v = Ms[(oc + 2 * j) * 65 + oi], m1v = Ms[(oc + 2 * j + 1) * 65 + oi];
            cvt2_hl(m0v, m1v, &hm[j], &lm[j]);
            hf[j] = cvt2_h(Fs[(oc + 2 * j) * 65 + oi], Fs[(oc + 2 * j + 1) * 65 + oi]);
        }
        const long ro = ((long)b * HW_ + i0 + oi) * C_ + c0 + oc;
        *reinterpret_cast<uint4*>(&mTh[ro])     = make_uint4(hm[0], hm[1], hm[2], hm[3]);
        *reinterpret_cast<uint4*>(&mTh[ro + 8]) = make_uint4(hm[4], hm[5], hm[6], hm[7]);
        *reinterpret_cast<uint4*>(&mTl[ro])     = make_uint4(lm[0], lm[1], lm[2], lm[3]);
        *reinterpret_cast<uint4*>(&mTl[ro + 8]) = make_uint4(lm[4], lm[5], lm[6], lm[7]);
        *reinterpret_cast<uint4*>(&fTh[ro])     = make_uint4(hf[0], hf[1], hf[2], hf[3]);
        *reinterpret_cast<uint4*>(&fTh[ro + 8]) = make_uint4(hf[4], hf[5], hf[6], hf[7]);
        return;
    }

    const int flat = blockIdx.y * 64 + blockIdx.x;   // 0..255
    if (flat < 128) {
        // ---------------- gemm_nt64 branch: T = S1 * Wk^T ----------------
        const int r0 = (flat >> 2) * 64;
        const int d0 = (flat & 3) * 64;
        float* As = SH;               // [BK64][LDT64]
        float* Bs = SH + BK64 * LDT64;

        const int tx  = t & 15, ty = t >> 4;
        const int tx4 = tx * 4, ty4 = ty * 4;
        const int am  = t >> 2, ak4 = (t & 3) * 4;

        float acc[4][4] = {};
        for (int k0 = 0; k0 < C_; k0 += BK64) {
            float4 av = *reinterpret_cast<const float4*>(&S1[(long)(r0 + am) * C_ + k0 + ak4]);
            float4 bw = *reinterpret_cast<const float4*>(&Wk[(long)(d0 + am) * C_ + k0 + ak4]);
            As[(ak4+0)*LDT64+am]=av.x; As[(ak4+1)*LDT64+am]=av.y;
            As[(ak4+2)*LDT64+am]=av.z; As[(ak4+3)*LDT64+am]=av.w;
            Bs[(ak4+0)*LDT64+am]=bw.x; Bs[(ak4+1)*LDT64+am]=bw.y;
            Bs[(ak4+2)*LDT64+am]=bw.z; Bs[(ak4+3)*LDT64+am]=bw.w;
            __syncthreads();
            #pragma unroll
            for (int kk = 0; kk < BK64; ++kk) {
                float4 a = *reinterpret_cast<const float4*>(&As[kk*LDT64 + ty4]);
                float4 x = *reinterpret_cast<const float4*>(&Bs[kk*LDT64 + tx4]);
                const float ar[4] = {a.x,a.y,a.z,a.w};
                const float xr[4] = {x.x,x.y,x.z,x.w};
                #pragma unroll
                for (int r = 0; r < 4; ++r)
                    #pragma unroll
                    for (int s = 0; s < 4; ++s)
                        acc[r][s] = fmaf(ar[r], xr[s], acc[r][s]);
            }
            __syncthreads();
        }
        #pragma unroll
        for (int r = 0; r < 4; ++r) {
            float4 o; o.x=acc[r][0]; o.y=acc[r][1]; o.z=acc[r][2]; o.w=acc[r][3];
            *reinterpret_cast<float4*>(&T[(long)(r0 + ty4 + r) * C_ + d0 + tx4]) = o;
        }
        return;
    }
    if (flat < 192) {
        // ---------------- conv_w branch: Wv -> bf16 hi ----------------
        const int i = ((flat - 128) * 256 + t) * 4;
        float4 v = *reinterpret_cast<const float4*>(&Wv[i]);
        uint h[2];
        cvt_h4(v, h);
        *reinterpret_cast<uint2*>(&Wvh[i]) = make_uint2(h[0], h[1]);
    }
}

// ===========================================================================
// Stats pass: 128x128 tile, m97-style K-loop: BOTH operand sides staged via
// global_load_lds (pre-swizzled source, linear LDS, swizzled ds_read).
// Single-buffered, 2 barriers/chunk. (256,2): 256-reg budget, no spill.
// ===========================================================================
__global__ __launch_bounds__(256, 2) void gemm_stats_mfma(
    const ushort* __restrict__ corrh, const ushort* __restrict__ corrl,
    const ushort* __restrict__ mTh,   const ushort* __restrict__ mTl,
    float* __restrict__ pmax, float* __restrict__ psum)
{
    __shared__ __align__(16) ushort S_[4][4096];   // Ah, Al, Bh, Bl [128r x 32k]
    __shared__ float pm[2][128], ps[2][128];

    const int b  = blockIdx.z;
    const int m0 = blockIdx.y * 128;
    const int n0 = blockIdx.x * 128;
    const ushort* Ahb = corrh + (long)b * C_ * C_;
    const ushort* Alb = corrl + (long)b * C_ * C_;
    const ushort* Bhb = mTh + (long)b * HW_ * C_;
    const ushort* Blb = mTl + (long)b * HW_ * C_;

    const int t    = threadIdx.x;
    const int lane = t & 63, w = t >> 6;
    const int col  = lane & 15, quad = lane >> 4;
    const int wm   = (w >> 1) * 64, wn = (w & 1) * 64;
    const int qsw  = (lane & 3) ^ ((lane >> 3) & 3);   // staging k-slot swizzle
    const int srw  = lane >> 2;                        // staging row-in-16

    int aoff[4], boff[4];
    #pragma unroll
    for (int tt = 0; tt < 4; ++tt) {
        const int rowA = wm + tt * 16 + col;
        aoff[tt] = rowA * 64 + ((quad ^ ((rowA >> 1) & 3)) << 4);
        const int rowB = wn + tt * 16 + col;
        boff[tt] = rowB * 64 + ((quad ^ ((rowB >> 1) & 3)) << 4);
    }

    f32x4 acc[4][4] = {};

    #pragma unroll 1
    for (int kc = 0; kc < NCH; ++kc) {
        const int kt = kc * BKT;
        #pragma unroll
        for (int gg = 0; gg < 2; ++gg) {
            const int rbase = w * 32 + gg * 16;
            const long rsrc = rbase + srw;
            GLOAD_LDS16(Ahb + (long)(m0 + rsrc) * C_ + kt + qsw * 8, &S_[0][rbase * 32]);
            GLOAD_LDS16(Alb + (long)(m0 + rsrc) * C_ + kt + qsw * 8, &S_[1][rbase * 32]);
            GLOAD_LDS16(Bhb + (long)(n0 + rsrc) * C_ + kt + qsw * 8, &S_[2][rbase * 32]);
            GLOAD_LDS16(Blb + (long)(n0 + rsrc) * C_ + kt + qsw * 8, &S_[3][rbase * 32]);
        }
        __syncthreads();

        bf16x8 ah[4], al[4], bh[4], bl[4];
        #pragma unroll
        for (int tt = 0; tt < 4; ++tt) {
            ah[tt] = *reinterpret_cast<const bf16x8*>((const char*)&S_[0][0] + aoff[tt]);
            al[tt] = *reinterpret_cast<const bf16x8*>((const char*)&S_[1][0] + aoff[tt]);
            bh[tt] = *reinterpret_cast<const bf16x8*>((const char*)&S_[2][0] + boff[tt]);
            bl[tt] = *reinterpret_cast<const bf16x8*>((const char*)&S_[3][0] + boff[tt]);
        }
        #pragma unroll
        for (int tj = 0; tj < 4; ++tj) {
            #pragma unroll
            for (int ti = 0; ti < 4; ++ti) {
                acc[ti][tj] = MFMA_BF16(ah[ti], bh[tj], acc[ti][tj]);
                acc[ti][tj] = MFMA_BF16(ah[ti], bl[tj], acc[ti][tj]);
                acc[ti][tj] = MFMA_BF16(al[ti], bh[tj], acc[ti][tj]);
            }
        }
        __syncthreads();
    }

    // per-tile softmax partials (max & sum-exp over this block's 128 i's)
    #pragma unroll
    for (int ti = 0; ti < 4; ++ti) {
        #pragma unroll
        for (int r = 0; r < 4; ++r) {
            float mx = fmaxf(fmaxf(acc[ti][0][r], acc[ti][1][r]),
                             fmaxf(acc[ti][2][r], acc[ti][3][r]));
            mx = fmaxf(mx, __shfl_xor(mx, 1));
            mx = fmaxf(mx, __shfl_xor(mx, 2));
            mx = fmaxf(mx, __shfl_xor(mx, 4));
            mx = fmaxf(mx, __shfl_xor(mx, 8));
            float se2 = __expf(acc[ti][0][r] - mx) + __expf(acc[ti][1][r] - mx)
                      + __expf(acc[ti][2][r] - mx) + __expf(acc[ti][3][r] - mx);
            se2 += __shfl_xor(se2, 1);
            se2 += __shfl_xor(se2, 2);
            se2 += __shfl_xor(se2, 4);
            se2 += __shfl_xor(se2, 8);
            if (col == 0) {
                const int rb = wm + ti * 16 + quad * 4 + r;
                pm[w & 1][rb] = mx;
                ps[w & 1][rb] = se2;
            }
        }
    }
    __syncthreads();
    if (t < 128) {
        const float a0 = pm[0][t], a1 = pm[1][t];
        const float gm = fmaxf(a0, a1);
        const float gs = ps[0][t] * __expf(a0 - gm) + ps[1][t] * __expf(a1 - gm);
        const long rowg = (long)b * C_ + m0 + t;
        pmax[rowg * NPB + blockIdx.x] = gm;
        psum[rowg * NPB + blockIdx.x] = gs;
    }
}

// ===========================================================================
// Fused final: 128x128 tile, m97-style K-loop (6 arrays staged via
// global_load_lds, single-buffered). (256,2): needs ~230 regs, fits.
// ===========================================================================
__global__ __launch_bounds__(256, 2) void gemm_fused_final(
    const ushort* __restrict__ corrh, const ushort* __restrict__ corrl,
    const ushort* __restrict__ Wvh,
    const ushort* __restrict__ mTh,   const ushort* __restrict__ mTl,
    const ushort* __restrict__ fTh,
    const float* __restrict__ mask,   const float* __restrict__ fg,
    const float* __restrict__ pmax,   const float* __restrict__ psum,
    const float* __restrict__ bv,     const float* __restrict__ gamma,
    float* __restrict__ out)
{
    __shared__ __align__(16) ushort S_[6][4096];   // Ah, Al, Aw, Bh, Bl, Bf
    __shared__ float sm[128], si[128];

    const int b  = blockIdx.z;
    const int m0 = blockIdx.y * 128;        // c
    const int n0 = blockIdx.x * 128;        // i
    const ushort* Ahb = corrh + (long)b * C_ * C_;
    const ushort* Alb = corrl + (long)b * C_ * C_;
    const ushort* Bhb = mTh + (long)b * HW_ * C_;
    const ushort* Blb = mTl + (long)b * HW_ * C_;
    const ushort* Bfb = fTh + (long)b * HW_ * C_;

    const int t    = threadIdx.x;
    const int lane = t & 63, w = t >> 6;
    const int col  = lane & 15, quad = lane >> 4;
    const int wm   = (w >> 1) * 64, wn = (w & 1) * 64;
    const int qsw  = (lane & 3) ^ ((lane >> 3) & 3);
    const int srw  = lane >> 2;

    // ---- coalesced softmax-stat combine: 2 lanes per row, 4x float4 each ----
    {
        const int row  = t >> 1;
        const int part = t & 1;
        const long rowg = (long)b * C_ + m0 + row;
        const float* pmr = pmax + rowg * NPB + part * 16;
        const float* psr = psum + rowg * NPB + part * 16;
        float4 pv[4], sv[4];
        #pragma unroll
        for (int j = 0; j < 4; ++j) {
            pv[j] = *reinterpret_cast<const float4*>(pmr + j * 4);
            sv[j] = *reinterpret_cast<const float4*>(psr + j * 4);
        }
        float gm = -INFINITY;
        #pragma unroll
        for (int j = 0; j < 4; ++j)
            gm = fmaxf(gm, fmaxf(fmaxf(pv[j].x, pv[j].y), fmaxf(pv[j].z, pv[j].w)));
        gm = fmaxf(gm, __shfl_xor(gm, 1));
        float gs = 0.0f;
        #pragma unroll
        for (int j = 0; j < 4; ++j) {
            gs += sv[j].x * __expf(pv[j].x - gm) + sv[j].y * __expf(pv[j].y - gm)
                + sv[j].z * __expf(pv[j].z - gm) + sv[j].w * __expf(pv[j].w - gm);
        }
        gs += __shfl_xor(gs, 1);
        sm[row] = gm;
        si[row] = 1.0f / gs;
    }

    int aoff[4], boff[4];
    #pragma unroll
    for (int tt = 0; tt < 4; ++tt) {
        const int rowA = wm + tt * 16 + col;
        aoff[tt] = rowA * 64 + ((quad ^ ((rowA >> 1) & 3)) << 4);
        const int rowB = wn + tt * 16 + col;
        boff[tt] = rowB * 64 + ((quad ^ ((rowB >> 1) & 3)) << 4);
    }

    f32x4 acc_s[4][4] = {};
    f32x4 acc_v[4][4] = {};

    #pragma unroll 1
    for (int kc = 0; kc < NCH; ++kc) {
        const int kt = kc * BKT;
        #pragma unroll
        for (int gg = 0; gg < 2; ++gg) {
            const int rbase = w * 32 + gg * 16;
            const long rsrc = rbase + srw;
            GLOAD_LDS16(Ahb + (long)(m0 + rsrc) * C_ + kt + qsw * 8, &S_[0][rbase * 32]);
            GLOAD_LDS16(Alb + (long)(m0 + rsrc) * C_ + kt + qsw * 8, &S_[1][rbase * 32]);
            GLOAD_LDS16(Wvh + (long)(m0 + rsrc) * C_ + kt + qsw * 8, &S_[2][rbase * 32]);
            GLOAD_LDS16(Bhb + (long)(n0 + rsrc) * C_ + kt + qsw * 8, &S_[3][rbase * 32]);
            GLOAD_LDS16(Blb + (long)(n0 + rsrc) * C_ + kt + qsw * 8, &S_[4][rbase * 32]);
            GLOAD_LDS16(Bfb + (long)(n0 + rsrc) * C_ + kt + qsw * 8, &S_[5][rbase * 32]);
        }
        __syncthreads();

        bf16x8 ah[4], al[4], aw[4], bh[4], bl[4], bf[4];
        #pragma unroll
        for (int tt = 0; tt < 4; ++tt) {
            ah[tt] = *reinterpret_cast<const bf16x8*>((const char*)&S_[0][0] + aoff[tt]);
            al[tt] = *reinterpret_cast<const bf16x8*>((const char*)&S_[1][0] + aoff[tt]);
            aw[tt] = *reinterpret_cast<const bf16x8*>((const char*)&S_[2][0] + aoff[tt]);
            bh[tt] = *reinterpret_cast<const bf16x8*>((const char*)&S_[3][0] + boff[tt]);
            bl[tt] = *reinterpret_cast<const bf16x8*>((const char*)&S_[4][0] + boff[tt]);
            bf[tt] = *reinterpret_cast<const bf16x8*>((const char*)&S_[5][0] + boff[tt]);
        }
        #pragma unroll
        for (int tj = 0; tj < 4; ++tj) {
            #pragma unroll
            for (int ti = 0; ti < 4; ++ti) {
                acc_s[ti][tj] = MFMA_BF16(ah[ti], bh[tj], acc_s[ti][tj]);
                acc_s[ti][tj] = MFMA_BF16(ah[ti], bl[tj], acc_s[ti][tj]);
                acc_s[ti][tj] = MFMA_BF16(al[ti], bh[tj], acc_s[ti][tj]);
                acc_v[ti][tj] = MFMA_BF16(aw[ti], bf[tj], acc_v[ti][tj]);
            }
        }
        __syncthreads();
    }

    // scores -> gamma-scaled probabilities
    const float g = gamma[0];
    #pragma unroll
    for (int ti = 0; ti < 4; ++ti) {
        #pragma unroll
        for (int r = 0; r < 4; ++r) {
            const int lrow = wm + ti * 16 + quad * 4 + r;
            const float mx  = sm[lrow];
            const float inv = si[lrow] * g;
            #pragma unroll
            for (int tj = 0; tj < 4; ++tj)
                acc_s[ti][tj][r] = __expf(acc_s[ti][tj][r] - mx) * inv;
        }
    }

    // epilogue
    #pragma unroll
    for (int ti = 0; ti < 4; ++ti) {
        const int m = m0 + wm + ti * 16 + quad * 4;
        #pragma unroll
        for (int r = 0; r < 4; ++r) {
            const float bvm = bv[m + r];
            #pragma unroll
            for (int tj = 0; tj < 4; ++tj) {
                const int n = n0 + wn + tj * 16 + col;
                const long e = (long)b * CHW_ + (long)(m + r) * HW_ + n;
                const float f  = fg[e];
                const float mk = mask[e];
                const float vv = acc_v[ti][tj][r] + bvm;
                out[e] = f * mk + (1.0f - mk) * acc_s[ti][tj][r] * vv;
            }
        }
    }
}

// corr = Wq*T + u*bk^T + bq*wh^T -> bf16 h/l.  u, wh computed inline.
__global__ __launch_bounds__(256) void gemm_nn64_rank1(
    const float* __restrict__ Wq, const float* __restrict__ T,
    const float* __restrict__ Wk, const float* __restrict__ bk,
    const float* __restrict__ bq,
    const float* __restrict__ fsum, const float* __restrict__ gsum,
    ushort* __restrict__ corrh, ushort* __restrict__ corrl)
{
    __shared__ float As[BK64][LDT64];
    __shared__ float Bs[BK64][LDT64];
    __shared__ float u_s[64], wh_s[64];
    const int b  = blockIdx.z;
    const int m0 = blockIdx.y * 64;
    const int n0 = blockIdx.x * 64;
    const float* Tb = T + (long)b * C_ * C_;

    const int t   = threadIdx.x;
    const int tx  = t & 15, ty = t >> 4;
    const int tx4 = tx * 4, ty4 = ty * 4;
    const int am  = t >> 2, ak4 = (t & 3) * 4;
    const int xk  = ty,     xn4 = tx4;

    if (t < 64) {
        const float* wrow = Wq + (long)(m0 + t) * C_;
        const float* s = fsum + b * C_;
        float a = 0.0f;
        for (int e2 = 0; e2 < C_; ++e2) a = fmaf(wrow[e2], s[e2], a);
        u_s[t] = a;
    } else if (t < 128) {
        const int d = n0 + (t - 64);
        const float* wrow = Wk + (long)d * C_;
        const float* s = gsum + b * C_;
        float a = 0.0f;
        for (int e2 = 0; e2 < C_; ++e2) a = fmaf(wrow[e2], s[e2], a);
        wh_s[t - 64] = a + (float)HW_ * bk[d];
    }

    float acc[4][4] = {};
    for (int k0 = 0; k0 < C_; k0 += BK64) {
        float4 av = *reinterpret_cast<const float4*>(&Wq[(long)(m0 + am) * C_ + k0 + ak4]);
        float4 xv = *reinterpret_cast<const float4*>(&Tb[(long)(k0 + xk) * C_ + n0 + xn4]);
        As[ak4+0][am]=av.x; As[ak4+1][am]=av.y; As[ak4+2][am]=av.z; As[ak4+3][am]=av.w;
        *reinterpret_cast<float4*>(&Bs[xk][xn4]) = xv;
        __syncthreads();
        #pragma unroll
        for (int kk = 0; kk < BK64; ++kk) {
            float4 a = *reinterpret_cast<const float4*>(&As[kk][ty4]);
            float4 x = *reinterpret_cast<const float4*>(&Bs[kk][tx4]);
            const float ar[4] = {a.x,a.y,a.z,a.w};
            const float xr[4] = {x.x,x.y,x.z,x.w};
            #pragma unroll
            for (int r = 0; r < 4; ++r)
                #pragma unroll
                for (int s = 0; s < 4; ++s)
                    acc[r][s] = fmaf(ar[r], xr[s], acc[r][s]);
        }
        __syncthreads();
    }

    float4 bkv = *reinterpret_cast<const float4*>(&bk[n0 + tx4]);
    float4 whv = make_float4(wh_s[tx4], wh_s[tx4+1], wh_s[tx4+2], wh_s[tx4+3]);
    #pragma unroll
    for (int r = 0; r < 4; ++r) {
        const int m = m0 + ty4 + r;
        const float um = u_s[ty4 + r];
        const float bm = bq[m];
        float4 o;
        o.x = acc[r][0] + um*bkv.x + bm*whv.x;
        o.y = acc[r][1] + um*bkv.y + bm*whv.y;
        o.z = acc[r][2] + um*bkv.z + bm*whv.z;
        o.w = acc[r][3] + um*bkv.w + bm*whv.w;
        uint h[2], l[2];
        cvt_hl4(o, h, l);
        const long e = (long)b * C_ * C_ + (long)m * C_ + n0 + tx4;
        *reinterpret_cast<uint2*>(&corrh[e]) = make_uint2(h[0], h[1]);
        *reinterpret_cast<uint2*>(&corrl[e]) = make_uint2(l[0], l[1]);
    }
}

// ===========================================================================
extern "C" void kernel_launch(void* const* d_in, const int* in_sizes, int n_in,
                              void* d_out, int out_size, void* d_ws, size_t ws_size,
                              hipStream_t stream)
{
    const float* fg    = (const float*)d_in[0];
    const float* bg    = (const float*)d_in[1];
    const float* mask  = (const float*)d_in[2];
    const float* Wq    = (const float*)d_in[3];
    const float* bq    = (const float*)d_in[4];
    const float* Wk    = (const float*)d_in[5];
    const float* bk    = (const float*)d_in[6];
    const float* Wv    = (const float*)d_in[7];
    const float* bv    = (const float*)d_in[8];
    const float* gamma = (const float*)d_in[9];
    float* out = (float*)d_out;

    // ---- workspace layout (bytes), total 57,294,848 ----
    // part (33.5 MB) dead after reduce_part -> aliased by mTh/mTl.
    // S1 (2 MB) dead after mid_pass's nt64 -> aliased by pmax/psum.
    char* ws = (char*)d_ws;
    float*  part   = (float*)(ws);                        // 33,554,432
    float*  S1     = (float*)(ws + 33554432);             // 2,097,152
    float*  T      = (float*)(ws + 35651584);             // 2,097,152
    ushort* corrh  = (ushort*)(ws + 37748736);            // 1,048,576
    ushort* corrl  = (ushort*)(ws + 38797312);            // 1,048,576
    ushort* Wvh    = (ushort*)(ws + 39845888);            // 131,072
    float*  fsum   = (float*)(ws + 39976960);             // 8,192
    float*  gsum   = (float*)(ws + 39985152);             // 8,192
    float*  pmax   = (float*)(ws + 33554432);             // 262,144 (alias S1)
    float*  psum   = (float*)(ws + 33816576);             // 262,144 (alias S1)
    ushort* mTh    = (ushort*)(ws);                       // 16,777,216 (alias part)
    ushort* mTl    = (ushort*)(ws + 16777216);            // 16,777,216 (alias part)
    ushort* fTh    = (ushort*)(ws + 40517632);            // 16,777,216

    const dim3 blk(256);

    // 0. zero the atomic accumulators (fsum+gsum contiguous 16 kB)
    hipMemsetAsync(fsum, 0, 16384, stream);

    // 1. S1 = F*G^T via split-K MFMA (fused row sums + reg prefetch), reduce
    gemm_nt_mfma<<<dim3(2, 2, B_ * KS), blk, 0, stream>>>(fg, bg, part, fsum, gsum);
    reduce_part<<<dim3(B_ * C_ * C_ / 1024), blk, 0, stream>>>(part, S1);

    // 2. merged: transpose_cvt + nt64 (T = S1*Wk^T) + conv_w — one launch
    mid_pass<<<dim3(HW_ / 64, C_ / 64, B_ + 1), blk, 0, stream>>>(
        mask, fg, mTh, mTl, fTh, S1, Wk, T, Wv, Wvh);

    // 3. corr (bf16 h/l) = Wq*T + u*bk^T + bq*wh^T (uvw inline)
    gemm_nn64_rank1<<<dim3(4, 4, B_), blk, 0, stream>>>(
        Wq, T, Wk, bk, bq, fsum, gsum, corrh, corrl);

    // 4. stats pass (128x128, both sides LDS-staged, m97-style)
    gemm_stats_mfma<<<dim3(HW_ / 128, C_ / 128, B_), blk, 0, stream>>>(
        corrh, corrl, mTh, mTl, pmax, psum);

    // 5. fused recompute + v-GEMM + finalize (128x128, both sides LDS-staged)
    gemm_fused_final<<<dim3(HW_ / 128, C_ / 128, B_), blk, 0, stream>>>(
        corrh, corrl, Wvh, mTh, mTl, fTh, mask, fg, pmax, psum, bv, gamma, out);
}